// Round 1
// baseline (394.995 us; speedup 1.0000x reference)
//
#include <hip/hip_runtime.h>
#include <hip/hip_bf16.h>
#include <stdint.h>

typedef short s16x8 __attribute__((ext_vector_type(8)));
typedef float f32x4 __attribute__((ext_vector_type(4)));

#define NB 4096
#define KTOT 24576
#define NOUT 512
#define NCH 48

__device__ __forceinline__ short f2bf(float f){
  union { float f; uint32_t u; } x; x.f = f;
  uint32_t r = (x.u + 0x7FFFu + ((x.u >> 16) & 1u)) >> 16;
  return (short)r;
}
__device__ __forceinline__ float bf2f(short s){
  union { uint32_t u; float f; } x; x.u = ((uint32_t)(uint16_t)s) << 16;
  return x.f;
}

// ---------------- kernel 0: column->channel map + zero bn0 accumulators ----
__global__ __launch_bounds__(256) void k_colmap(const int* __restrict__ perm,
                                                int* __restrict__ chmap,
                                                float* __restrict__ statf){
  int q = blockIdx.x * 256 + threadIdx.x;
  if (q < 1024) chmap[perm[q]] = q >> 9;
  if (blockIdx.x == 0 && threadIdx.x < 4) statf[threadIdx.x] = 0.f;
}

// ---------------- kernel 1: bn0 batch stats ------------------------------
__global__ __launch_bounds__(256) void k_bn0(const float* __restrict__ concat,
                                             const int* __restrict__ chmap,
                                             float* __restrict__ statf){
  int t = threadIdx.x;
  float s0=0,q0=0,s1=0,q1=0;
  for (int idx = blockIdx.x*256 + t; idx < NB*1024; idx += gridDim.x*256){
    float v = concat[idx];
    int ch = chmap[idx & 1023];
    if (ch){ s1 += v; q1 += v*v; } else { s0 += v; q0 += v*v; }
  }
  #pragma unroll
  for (int m=1;m<64;m<<=1){
    s0 += __shfl_xor(s0,m); q0 += __shfl_xor(q0,m);
    s1 += __shfl_xor(s1,m); q1 += __shfl_xor(q1,m);
  }
  __shared__ float lb[4][4];
  int wid = t>>6, lane = t&63;
  if (lane==0){ lb[wid][0]=s0; lb[wid][1]=q0; lb[wid][2]=s1; lb[wid][3]=q1; }
  __syncthreads();
  if (t==0){
    float a0=0,a1=0,a2=0,a3=0;
    #pragma unroll
    for (int w=0;w<4;w++){ a0+=lb[w][0]; a1+=lb[w][1]; a2+=lb[w][2]; a3+=lb[w][3]; }
    atomicAdd(&statf[0],a0); atomicAdd(&statf[1],a1);
    atomicAdd(&statf[2],a2); atomicAdd(&statf[3],a3);
  }
}

// ---------------- kernel 2: cast+transpose fc_W -> wT[n][k] bf16 ----------
__global__ __launch_bounds__(256) void k_wcast(const float* __restrict__ fcW,
                                               short* __restrict__ wT){
  __shared__ float tile[64][65];
  int bid = blockIdx.x;
  int kb = (bid % 384) * 64;
  int nb = (bid / 384) * 64;
  int t = threadIdx.x;
  #pragma unroll
  for (int i=0;i<16;i++){
    int r = i*4 + (t>>6), c = t & 63;
    tile[r][c] = fcW[(size_t)(kb + r)*NOUT + nb + c];
  }
  __syncthreads();
  #pragma unroll
  for (int i=0;i<16;i++){
    int n = i*4 + (t>>6), k = t & 63;
    wT[(size_t)(nb + n)*KTOT + kb + k] = f2bf(tile[k][n]);
  }
}

// ---------------- kernel 3: per-sample conv (3 branches) ------------------
__global__ __launch_bounds__(256) void k_conv(
    const float* __restrict__ concat, const int* __restrict__ perm,
    const int* __restrict__ rel,
    const float* __restrict__ f1t, const float* __restrict__ f3t,
    const float* __restrict__ f5t,
    const float* __restrict__ statf,
    const float* __restrict__ bn0g, const float* __restrict__ bn0b,
    short* __restrict__ raw, float* __restrict__ psum, float* __restrict__ psq)
{
  const int b = blockIdx.x;
  const int t = threadIdx.x;
  __shared__ float xn[2*9*9*9];     // padded [2][9][9][9], pad = 0
  __shared__ float filt[448];
  for (int i=t;i<1458;i+=256) xn[i]=0.f;
  int r = rel[b];
  for (int i=t;i<448;i+=256){
    float v;
    if (i < 64)       v = f1t[r*64 + i];
    else if (i < 192) v = f3t[r*128 + (i-64)];
    else              v = f5t[r*256 + (i-192)];
    filt[i]=v;
  }
  __syncthreads();
  const float n0inv = 1.f/(4096.f*512.f);
  float m0 = statf[0]*n0inv, e0 = statf[1]*n0inv;
  float m1 = statf[2]*n0inv, e1 = statf[3]*n0inv;
  float sc0 = bn0g[0]*rsqrtf(e0-m0*m0+1e-5f), sh0 = bn0b[0]-m0*sc0;
  float sc1 = bn0g[1]*rsqrtf(e1-m1*m1+1e-5f), sh1 = bn0b[1]-m1*sc1;
  for (int q=t;q<1024;q+=256){
    int col = perm[q];
    float v = concat[(size_t)b*1024 + col];
    int ch = q>>9, s = q & 511;
    int d = s>>6, h=(s>>3)&7, w=s&7;
    xn[ch*729 + d*81 + h*9 + w] = ch ? v*sc1+sh1 : v*sc0+sh0;
  }
  __syncthreads();

  const int wid = t>>6, lane = t&63;
  const int d = lane>>3, h = lane&7;
  // tap rows: r{kd*2+kh}{ci}[w], 9 wide (index 8 = zero pad)
  float r00[9], r01[9], r10[9], r11[9], r20[9], r21[9], r30[9], r31[9];
  #pragma unroll
  for (int w9=0;w9<9;w9++){
    int base0 = d*81 + h*9 + w9;
    int base1 = d*81 + (h+1)*9 + w9;
    int base2 = (d+1)*81 + h*9 + w9;
    int base3 = (d+1)*81 + (h+1)*9 + w9;
    r00[w9]=xn[base0];      r01[w9]=xn[729+base0];
    r10[w9]=xn[base1];      r11[w9]=xn[729+base1];
    r20[w9]=xn[base2];      r21[w9]=xn[729+base2];
    r30[w9]=xn[base3];      r31[w9]=xn[729+base3];
  }
  const size_t rawbase = (size_t)b*KTOT;

  auto finish = [&](int c, const float* v){
    float s=0,q=0;
    #pragma unroll
    for (int p=0;p<8;p++){ s += v[p]; q += v[p]*v[p]; }
    #pragma unroll
    for (int m=1;m<64;m<<=1){ s += __shfl_xor(s,m); q += __shfl_xor(q,m); }
    if (lane==0){ psum[c*NB+b]=s; psq[c*NB+b]=q; }
    s16x8 pk;
    #pragma unroll
    for (int p=0;p<8;p++) pk[p] = f2bf(v[p]);
    *reinterpret_cast<s16x8*>(raw + rawbase + (size_t)c*512 + lane*8) = pk;
  };

  // branch 0 (f1: ci,kw)
  #pragma unroll
  for (int i=0;i<4;i++){
    int oc = wid + 4*i;
    float c0=filt[oc*4+0], c1=filt[oc*4+1], c2=filt[oc*4+2], c3=filt[oc*4+3];
    float v[8];
    #pragma unroll
    for (int p=0;p<8;p++)
      v[p] = c0*r00[p]+c1*r00[p+1]+c2*r01[p]+c3*r01[p+1];
    finish(oc, v);
  }
  // branch 1 (f3: ci,kh,kw)
  #pragma unroll
  for (int i=0;i<4;i++){
    int oc = wid + 4*i;
    const float* cf = &filt[64 + oc*8];
    float v[8];
    #pragma unroll
    for (int p=0;p<8;p++)
      v[p] = cf[0]*r00[p]+cf[1]*r00[p+1]+cf[2]*r10[p]+cf[3]*r10[p+1]
           + cf[4]*r01[p]+cf[5]*r01[p+1]+cf[6]*r11[p]+cf[7]*r11[p+1];
    finish(16+oc, v);
  }
  // branch 2 (f5: ci,kd,kh,kw)
  #pragma unroll
  for (int i=0;i<4;i++){
    int oc = wid + 4*i;
    const float* cf = &filt[192 + oc*16];
    float v[8];
    #pragma unroll
    for (int p=0;p<8;p++)
      v[p] = cf[0]*r00[p] +cf[1]*r00[p+1] +cf[2]*r10[p] +cf[3]*r10[p+1]
           + cf[4]*r20[p] +cf[5]*r20[p+1] +cf[6]*r30[p] +cf[7]*r30[p+1]
           + cf[8]*r01[p] +cf[9]*r01[p+1] +cf[10]*r11[p]+cf[11]*r11[p+1]
           + cf[12]*r21[p]+cf[13]*r21[p+1]+cf[14]*r31[p]+cf[15]*r31[p+1];
    finish(32+oc, v);
  }
}

// ---------------- kernel 4: finalize bn1/2/3 scale+shift ------------------
__global__ __launch_bounds__(256) void k_bnstats(
    const float* __restrict__ psum, const float* __restrict__ psq,
    const float* __restrict__ bn1g, const float* __restrict__ bn1b,
    const float* __restrict__ bn2g, const float* __restrict__ bn2b,
    const float* __restrict__ bn3g, const float* __restrict__ bn3b,
    float* __restrict__ statf)
{
  int c = blockIdx.x, t = threadIdx.x;
  float s=0,q=0;
  for (int b=t;b<NB;b+=256){ s += psum[c*NB+b]; q += psq[c*NB+b]; }
  #pragma unroll
  for (int m=1;m<64;m<<=1){ s += __shfl_xor(s,m); q += __shfl_xor(q,m); }
  __shared__ float lb[4][2];
  int wid = t>>6, lane = t&63;
  if (lane==0){ lb[wid][0]=s; lb[wid][1]=q; }
  __syncthreads();
  if (t==0){
    s = lb[0][0]+lb[1][0]+lb[2][0]+lb[3][0];
    q = lb[0][1]+lb[1][1]+lb[2][1]+lb[3][1];
    float n = 4096.f*512.f;
    float mean = s/n, var = q/n - mean*mean;
    const float* g  = c<16 ? bn1g : (c<32 ? bn2g : bn3g);
    const float* bb = c<16 ? bn1b : (c<32 ? bn2b : bn3b);
    int oc = c & 15;
    float sc = g[oc]*rsqrtf(var + 1e-5f);
    statf[16+c] = sc;
    statf[64+c] = bb[oc] - mean*sc;
  }
}

// ---------------- kernel 5: SE gates --------------------------------------
__global__ __launch_bounds__(64) void k_se(
    const float* __restrict__ psum, const float* __restrict__ statf,
    const float* __restrict__ Wsq, const float* __restrict__ bsq,
    const float* __restrict__ W1, const float* __restrict__ b1,
    const float* __restrict__ W2, const float* __restrict__ b2,
    const float* __restrict__ W3, const float* __restrict__ b3,
    float* __restrict__ gates)
{
  int b = blockIdx.x, lane = threadIdx.x;
  __shared__ float pooled[16];
  __shared__ float zq[32];
  if (lane < 16){
    float p = 0.f;
    #pragma unroll
    for (int br=0;br<3;br++){
      int c = br*16 + lane;
      p += psum[c*NB+b]*(1.f/512.f)*statf[16+c] + statf[64+c];
    }
    pooled[lane] = p;
  }
  __syncthreads();
  if (lane < 32){
    float z = bsq[lane];
    #pragma unroll
    for (int oc=0;oc<16;oc++) z += pooled[oc]*Wsq[oc*32+lane];
    zq[lane] = fmaxf(z, 0.f);
  }
  __syncthreads();
  if (lane < 48){
    int br = lane>>4, oc = lane&15;
    const float* W  = br==0 ? W1 : (br==1 ? W2 : W3);
    const float* bb = br==0 ? b1 : (br==1 ? b2 : b3);
    float g = bb[oc];
    #pragma unroll
    for (int r2=0;r2<32;r2++) g += zq[r2]*W[r2*16+oc];
    gates[lane*NB + b] = 1.f/(1.f + expf(-g));
  }
}

// ---------------- kernel 6: fused bn+gate+relu GEMM (split-K) -------------
// C[4096,512] = A[4096,24576] @ W[24576,512];  A = relu(raw*sc+sh)*gate
__global__ __launch_bounds__(512) void k_gemm(
    const short* __restrict__ raw, const short* __restrict__ wT,
    const float* __restrict__ scale, const float* __restrict__ shift,
    const float* __restrict__ gates, float* __restrict__ partials)
{
  const int t = threadIdx.x;
  const int bid = blockIdx.x;
  const int sk = bid >> 6, rem = bid & 63;
  const int nblk = rem >> 5, mblk = rem & 31;
  const int b0 = mblk*128, n0 = nblk*256;
  const int kb0 = sk*6144;

  __shared__ short As[128][40];   // 80B rows -> conflict-free b128
  __shared__ short Ws[256][40];

  const int arow = t>>2, acol = (t&3)<<3;
  const int wrow = t>>1, wcol = (t&1)<<4;
  const short* aptr = raw + (size_t)(b0+arow)*KTOT + kb0 + acol;
  const short* wptr = wT  + (size_t)(n0+wrow)*KTOT + kb0 + wcol;

  f32x4 acc[4][4];
  #pragma unroll
  for (int m=0;m<4;m++)
    #pragma unroll
    for (int n=0;n<4;n++){ f32x4 z = {0.f,0.f,0.f,0.f}; acc[m][n]=z; }

  const int wid = t>>6, lane = t&63;
  const int wr = (wid>>2)*64, wc = (wid&3)*64;
  const int fr = lane&15, fk = (lane>>4)<<3;

  s16x8 aReg  = *reinterpret_cast<const s16x8*>(aptr);
  s16x8 wReg0 = *reinterpret_cast<const s16x8*>(wptr);
  s16x8 wReg1 = *reinterpret_cast<const s16x8*>(wptr+8);
  float gateReg = gates[(kb0>>9)*NB + b0 + arow];
  float scReg = scale[kb0>>9], shReg = shift[kb0>>9];

  for (int step=0; step<192; ++step){
    s16x8 av;
    #pragma unroll
    for (int j=0;j<8;j++){
      float x = bf2f(aReg[j]);
      x = fmaxf(x*scReg + shReg, 0.f)*gateReg;
      av[j] = f2bf(x);
    }
    *reinterpret_cast<s16x8*>(&As[arow][acol])   = av;
    *reinterpret_cast<s16x8*>(&Ws[wrow][wcol])   = wReg0;
    *reinterpret_cast<s16x8*>(&Ws[wrow][wcol+8]) = wReg1;
    if (step < 191){
      int off = (step+1)*32;
      aReg  = *reinterpret_cast<const s16x8*>(aptr + off);
      wReg0 = *reinterpret_cast<const s16x8*>(wptr + off);
      wReg1 = *reinterpret_cast<const s16x8*>(wptr + off + 8);
      int kn = kb0 + off;
      gateReg = gates[(kn>>9)*NB + b0 + arow];
      scReg = scale[kn>>9]; shReg = shift[kn>>9];
    }
    __syncthreads();
    s16x8 af[4], bfm[4];
    #pragma unroll
    for (int m=0;m<4;m++) af[m]  = *reinterpret_cast<const s16x8*>(&As[wr + m*16 + fr][fk]);
    #pragma unroll
    for (int n=0;n<4;n++) bfm[n] = *reinterpret_cast<const s16x8*>(&Ws[wc + n*16 + fr][fk]);
    #pragma unroll
    for (int m=0;m<4;m++)
      #pragma unroll
      for (int n=0;n<4;n++)
        acc[m][n] = __builtin_amdgcn_mfma_f32_16x16x32_bf16(af[m], bfm[n], acc[m][n], 0,0,0);
    __syncthreads();
  }

  float* pbase = partials + (size_t)sk*NB*NOUT;
  #pragma unroll
  for (int m=0;m<4;m++){
    #pragma unroll
    for (int j=0;j<4;j++){
      int row = b0 + wr + m*16 + (lane>>4)*4 + j;
      float* prow = pbase + (size_t)row*NOUT + n0 + wc + fr;
      #pragma unroll
      for (int n=0;n<4;n++) prow[n*16] = acc[m][n][j];
    }
  }
}

// ---------------- kernel 7: split-K reduce + bias -------------------------
__global__ __launch_bounds__(256) void k_red(const float* __restrict__ partials,
                                             const float* __restrict__ fcb,
                                             float* __restrict__ out){
  int i = blockIdx.x*256 + threadIdx.x;          // float4 index, 524288 total
  const f32x4* p = reinterpret_cast<const f32x4*>(partials);
  f32x4 v = p[i];
  v += p[i + 524288];
  v += p[i + 2*524288];
  v += p[i + 3*524288];
  const f32x4 bias = *reinterpret_cast<const f32x4*>(fcb + ((i*4) & 511));
  v += bias;
  reinterpret_cast<f32x4*>(out)[i] = v;
}

// ---------------- launch ---------------------------------------------------
extern "C" void kernel_launch(void* const* d_in, const int* in_sizes, int n_in,
                              void* d_out, int out_size, void* d_ws, size_t ws_size,
                              hipStream_t stream) {
  const float* concat = (const float*)d_in[0];
  const int*   rel    = (const int*)  d_in[1];
  const int*   perm   = (const int*)  d_in[2];
  const float* f1t = (const float*)d_in[3];
  const float* f3t = (const float*)d_in[4];
  const float* f5t = (const float*)d_in[5];
  const float* bn0g=(const float*)d_in[6],  *bn0b=(const float*)d_in[7];
  const float* bn1g=(const float*)d_in[8],  *bn1b=(const float*)d_in[9];
  const float* bn2g=(const float*)d_in[10], *bn2b=(const float*)d_in[11];
  const float* bn3g=(const float*)d_in[12], *bn3b=(const float*)d_in[13];
  const float* Wsq=(const float*)d_in[14],  *bsq=(const float*)d_in[15];
  const float* W1=(const float*)d_in[16],   *b1=(const float*)d_in[17];
  const float* W2=(const float*)d_in[18],   *b2=(const float*)d_in[19];
  const float* W3=(const float*)d_in[20],   *b3=(const float*)d_in[21];
  const float* fcW=(const float*)d_in[22],  *fcb=(const float*)d_in[23];
  float* out = (float*)d_out;
  char* ws = (char*)d_ws;

  const size_t off_raw  = 0;                         // 4096*24576*2 = 201326592
  const size_t off_wT   = 201326592;                 // 512*24576*2  = 25165824
  const size_t off_part = 226492416;                 // 4*4096*512*4 = 33554432
  const size_t off_psum = 260046848;                 // 48*4096*4    = 786432
  const size_t off_psq  = 260833280;                 // 786432
  const size_t off_gate = 261619712;                 // 786432
  const size_t off_stat = 262406144;                 // 512
  const size_t off_chm  = 262406656;                 // 4096
  const size_t need     = off_chm + 4096;
  if (ws_size < need) return;  // diagnose: output stays zero -> absmax ~2.86

  short* raw      = (short*)(ws + off_raw);
  short* wT       = (short*)(ws + off_wT);
  float* partials = (float*)(ws + off_part);
  float* psum     = (float*)(ws + off_psum);
  float* psq      = (float*)(ws + off_psq);
  float* gates    = (float*)(ws + off_gate);
  float* statf    = (float*)(ws + off_stat);
  int*   chmap    = (int*)  (ws + off_chm);

  k_colmap<<<4, 256, 0, stream>>>(perm, chmap, statf);
  k_bn0   <<<2048, 256, 0, stream>>>(concat, chmap, statf);
  k_wcast <<<3072, 256, 0, stream>>>(fcW, wT);
  k_conv  <<<4096, 256, 0, stream>>>(concat, perm, rel, f1t, f3t, f5t,
                                     statf, bn0g, bn0b, raw, psum, psq);
  k_bnstats<<<48, 256, 0, stream>>>(psum, psq, bn1g, bn1b, bn2g, bn2b,
                                    bn3g, bn3b, statf);
  k_se    <<<4096, 64, 0, stream>>>(psum, statf, Wsq, bsq, W1, b1, W2, b2,
                                    W3, b3, gates);
  k_gemm  <<<256, 512, 0, stream>>>(raw, wT, statf+16, statf+64, gates, partials);
  k_red   <<<2048, 256, 0, stream>>>(partials, fcb, out);
}

// Round 2
// 362.733 us; speedup vs baseline: 1.0889x; 1.0889x over previous
//
#include <hip/hip_runtime.h>
#include <hip/hip_bf16.h>
#include <stdint.h>

typedef short s16x8 __attribute__((ext_vector_type(8)));
typedef short s16x4 __attribute__((ext_vector_type(4)));
typedef float f32x4 __attribute__((ext_vector_type(4)));

#define NB 4096
#define KTOT 24576
#define NOUT 512
#define NCH 48

__device__ __forceinline__ short f2bf(float f){
  union { float f; uint32_t u; } x; x.f = f;
  uint32_t r = (x.u + 0x7FFFu + ((x.u >> 16) & 1u)) >> 16;
  return (short)r;
}
__device__ __forceinline__ float bf2f(short s){
  union { uint32_t u; float f; } x; x.u = ((uint32_t)(uint16_t)s) << 16;
  return x.f;
}
__device__ __forceinline__ short f2bf_fast(float x){
  union { __hip_bfloat16 h; short s; } c; c.h = __float2bfloat16(x); return c.s;
}

#define GLOAD16(g, l) __builtin_amdgcn_global_load_lds( \
  (const __attribute__((address_space(1))) void*)(g), \
  (__attribute__((address_space(3))) void*)(l), 16, 0, 0)

// ---------------- kernel 0: column->channel map + zero bn0 accumulators ----
__global__ __launch_bounds__(256) void k_colmap(const int* __restrict__ perm,
                                                int* __restrict__ chmap,
                                                float* __restrict__ statf){
  int q = blockIdx.x * 256 + threadIdx.x;
  if (q < 1024) chmap[perm[q]] = q >> 9;
  if (blockIdx.x == 0 && threadIdx.x < 4) statf[threadIdx.x] = 0.f;
}

// ---------------- kernel 1: bn0 batch stats ------------------------------
__global__ __launch_bounds__(256) void k_bn0(const float* __restrict__ concat,
                                             const int* __restrict__ chmap,
                                             float* __restrict__ statf){
  int t = threadIdx.x;
  float s0=0,q0=0,s1=0,q1=0;
  for (int idx = blockIdx.x*256 + t; idx < NB*1024; idx += gridDim.x*256){
    float v = concat[idx];
    int ch = chmap[idx & 1023];
    if (ch){ s1 += v; q1 += v*v; } else { s0 += v; q0 += v*v; }
  }
  #pragma unroll
  for (int m=1;m<64;m<<=1){
    s0 += __shfl_xor(s0,m); q0 += __shfl_xor(q0,m);
    s1 += __shfl_xor(s1,m); q1 += __shfl_xor(q1,m);
  }
  __shared__ float lb[4][4];
  int wid = t>>6, lane = t&63;
  if (lane==0){ lb[wid][0]=s0; lb[wid][1]=q0; lb[wid][2]=s1; lb[wid][3]=q1; }
  __syncthreads();
  if (t==0){
    float a0=0,a1=0,a2=0,a3=0;
    #pragma unroll
    for (int w=0;w<4;w++){ a0+=lb[w][0]; a1+=lb[w][1]; a2+=lb[w][2]; a3+=lb[w][3]; }
    atomicAdd(&statf[0],a0); atomicAdd(&statf[1],a1);
    atomicAdd(&statf[2],a2); atomicAdd(&statf[3],a3);
  }
}

// ---------------- kernel 2: cast+transpose fc_W -> wT[n][k] bf16 ----------
__global__ __launch_bounds__(256) void k_wcast(const float* __restrict__ fcW,
                                               short* __restrict__ wT){
  __shared__ float tile[64][65];
  int bid = blockIdx.x;
  int kb = (bid % 384) * 64;
  int nb = (bid / 384) * 64;
  int t = threadIdx.x;
  #pragma unroll
  for (int i=0;i<16;i++){
    int r = i*4 + (t>>6), c = t & 63;
    tile[r][c] = fcW[(size_t)(kb + r)*NOUT + nb + c];
  }
  __syncthreads();
  #pragma unroll
  for (int i=0;i<16;i++){
    int n = i*4 + (t>>6), k = t & 63;
    wT[(size_t)(nb + n)*KTOT + kb + k] = f2bf(tile[k][n]);
  }
}

// ---------------- kernel 3: per-sample conv (3 branches) ------------------
__global__ __launch_bounds__(256) void k_conv(
    const float* __restrict__ concat, const int* __restrict__ perm,
    const int* __restrict__ rel,
    const float* __restrict__ f1t, const float* __restrict__ f3t,
    const float* __restrict__ f5t,
    const float* __restrict__ statf,
    const float* __restrict__ bn0g, const float* __restrict__ bn0b,
    short* __restrict__ raw, float* __restrict__ psum, float* __restrict__ psq)
{
  const int b = blockIdx.x;
  const int t = threadIdx.x;
  __shared__ float xn[2*9*9*9];     // padded [2][9][9][9], pad = 0
  __shared__ float filt[448];
  for (int i=t;i<1458;i+=256) xn[i]=0.f;
  int r = rel[b];
  for (int i=t;i<448;i+=256){
    float v;
    if (i < 64)       v = f1t[r*64 + i];
    else if (i < 192) v = f3t[r*128 + (i-64)];
    else              v = f5t[r*256 + (i-192)];
    filt[i]=v;
  }
  __syncthreads();
  const float n0inv = 1.f/(4096.f*512.f);
  float m0 = statf[0]*n0inv, e0 = statf[1]*n0inv;
  float m1 = statf[2]*n0inv, e1 = statf[3]*n0inv;
  float sc0 = bn0g[0]*rsqrtf(e0-m0*m0+1e-5f), sh0 = bn0b[0]-m0*sc0;
  float sc1 = bn0g[1]*rsqrtf(e1-m1*m1+1e-5f), sh1 = bn0b[1]-m1*sc1;
  for (int q=t;q<1024;q+=256){
    int col = perm[q];
    float v = concat[(size_t)b*1024 + col];
    int ch = q>>9, s = q & 511;
    int d = s>>6, h=(s>>3)&7, w=s&7;
    xn[ch*729 + d*81 + h*9 + w] = ch ? v*sc1+sh1 : v*sc0+sh0;
  }
  __syncthreads();

  const int wid = t>>6, lane = t&63;
  const int d = lane>>3, h = lane&7;
  float r00[9], r01[9], r10[9], r11[9], r20[9], r21[9], r30[9], r31[9];
  #pragma unroll
  for (int w9=0;w9<9;w9++){
    int base0 = d*81 + h*9 + w9;
    int base1 = d*81 + (h+1)*9 + w9;
    int base2 = (d+1)*81 + h*9 + w9;
    int base3 = (d+1)*81 + (h+1)*9 + w9;
    r00[w9]=xn[base0];      r01[w9]=xn[729+base0];
    r10[w9]=xn[base1];      r11[w9]=xn[729+base1];
    r20[w9]=xn[base2];      r21[w9]=xn[729+base2];
    r30[w9]=xn[base3];      r31[w9]=xn[729+base3];
  }
  const size_t rawbase = (size_t)b*KTOT;

  auto finish = [&](int c, const float* v){
    float s=0,q=0;
    #pragma unroll
    for (int p=0;p<8;p++){ s += v[p]; q += v[p]*v[p]; }
    #pragma unroll
    for (int m=1;m<64;m<<=1){ s += __shfl_xor(s,m); q += __shfl_xor(q,m); }
    if (lane==0){ psum[c*NB+b]=s; psq[c*NB+b]=q; }
    s16x8 pk;
    #pragma unroll
    for (int p=0;p<8;p++) pk[p] = f2bf(v[p]);
    *reinterpret_cast<s16x8*>(raw + rawbase + (size_t)c*512 + lane*8) = pk;
  };

  #pragma unroll
  for (int i=0;i<4;i++){
    int oc = wid + 4*i;
    float c0=filt[oc*4+0], c1=filt[oc*4+1], c2=filt[oc*4+2], c3=filt[oc*4+3];
    float v[8];
    #pragma unroll
    for (int p=0;p<8;p++)
      v[p] = c0*r00[p]+c1*r00[p+1]+c2*r01[p]+c3*r01[p+1];
    finish(oc, v);
  }
  #pragma unroll
  for (int i=0;i<4;i++){
    int oc = wid + 4*i;
    const float* cf = &filt[64 + oc*8];
    float v[8];
    #pragma unroll
    for (int p=0;p<8;p++)
      v[p] = cf[0]*r00[p]+cf[1]*r00[p+1]+cf[2]*r10[p]+cf[3]*r10[p+1]
           + cf[4]*r01[p]+cf[5]*r01[p+1]+cf[6]*r11[p]+cf[7]*r11[p+1];
    finish(16+oc, v);
  }
  #pragma unroll
  for (int i=0;i<4;i++){
    int oc = wid + 4*i;
    const float* cf = &filt[192 + oc*16];
    float v[8];
    #pragma unroll
    for (int p=0;p<8;p++)
      v[p] = cf[0]*r00[p] +cf[1]*r00[p+1] +cf[2]*r10[p] +cf[3]*r10[p+1]
           + cf[4]*r20[p] +cf[5]*r20[p+1] +cf[6]*r30[p] +cf[7]*r30[p+1]
           + cf[8]*r01[p] +cf[9]*r01[p+1] +cf[10]*r11[p]+cf[11]*r11[p+1]
           + cf[12]*r21[p]+cf[13]*r21[p+1]+cf[14]*r31[p]+cf[15]*r31[p+1];
    finish(32+oc, v);
  }
}

// ---------------- kernel 4: finalize bn1/2/3 scale+shift ------------------
__global__ __launch_bounds__(256) void k_bnstats(
    const float* __restrict__ psum, const float* __restrict__ psq,
    const float* __restrict__ bn1g, const float* __restrict__ bn1b,
    const float* __restrict__ bn2g, const float* __restrict__ bn2b,
    const float* __restrict__ bn3g, const float* __restrict__ bn3b,
    float* __restrict__ statf)
{
  int c = blockIdx.x, t = threadIdx.x;
  float s=0,q=0;
  for (int b=t;b<NB;b+=256){ s += psum[c*NB+b]; q += psq[c*NB+b]; }
  #pragma unroll
  for (int m=1;m<64;m<<=1){ s += __shfl_xor(s,m); q += __shfl_xor(q,m); }
  __shared__ float lb[4][2];
  int wid = t>>6, lane = t&63;
  if (lane==0){ lb[wid][0]=s; lb[wid][1]=q; }
  __syncthreads();
  if (t==0){
    s = lb[0][0]+lb[1][0]+lb[2][0]+lb[3][0];
    q = lb[0][1]+lb[1][1]+lb[2][1]+lb[3][1];
    float n = 4096.f*512.f;
    float mean = s/n, var = q/n - mean*mean;
    const float* g  = c<16 ? bn1g : (c<32 ? bn2g : bn3g);
    const float* bb = c<16 ? bn1b : (c<32 ? bn2b : bn3b);
    int oc = c & 15;
    float sc = g[oc]*rsqrtf(var + 1e-5f);
    statf[16+c] = sc;
    statf[64+c] = bb[oc] - mean*sc;
  }
}

// ---------------- kernel 5: SE gates --------------------------------------
__global__ __launch_bounds__(64) void k_se(
    const float* __restrict__ psum, const float* __restrict__ statf,
    const float* __restrict__ Wsq, const float* __restrict__ bsq,
    const float* __restrict__ W1, const float* __restrict__ b1,
    const float* __restrict__ W2, const float* __restrict__ b2,
    const float* __restrict__ W3, const float* __restrict__ b3,
    float* __restrict__ gates)
{
  int b = blockIdx.x, lane = threadIdx.x;
  __shared__ float pooled[16];
  __shared__ float zq[32];
  if (lane < 16){
    float p = 0.f;
    #pragma unroll
    for (int br=0;br<3;br++){
      int c = br*16 + lane;
      p += psum[c*NB+b]*(1.f/512.f)*statf[16+c] + statf[64+c];
    }
    pooled[lane] = p;
  }
  __syncthreads();
  if (lane < 32){
    float z = bsq[lane];
    #pragma unroll
    for (int oc=0;oc<16;oc++) z += pooled[oc]*Wsq[oc*32+lane];
    zq[lane] = fmaxf(z, 0.f);
  }
  __syncthreads();
  if (lane < 48){
    int br = lane>>4, oc = lane&15;
    const float* W  = br==0 ? W1 : (br==1 ? W2 : W3);
    const float* bb = br==0 ? b1 : (br==1 ? b2 : b3);
    float g = bb[oc];
    #pragma unroll
    for (int r2=0;r2<32;r2++) g += zq[r2]*W[r2*16+oc];
    gates[lane*NB + b] = 1.f/(1.f + expf(-g));
  }
}

// ---------------- kernel 6: fused bn+gate+relu GEMM (split-K=8) -----------
// C[4096,512] = A[4096,24576] @ W[24576,512];  A = relu(raw*(sc*g)+(sh*g))
// tile 128x256, BK=32, 512 thr, double-buffered LDS, W via global_load_lds
__global__ __launch_bounds__(512, 4) void k_gemm(
    const short* __restrict__ raw, const short* __restrict__ wT,
    const float* __restrict__ scale, const float* __restrict__ shift,
    const float* __restrict__ gates, short* __restrict__ partials)
{
  const int t = threadIdx.x;
  const int bid = blockIdx.x;
  const int sk = bid >> 6, rem = bid & 63;
  const int nblk = rem >> 5, mblk = rem & 31;
  const int b0 = mblk*128, n0 = nblk*256;
  const int kb0 = sk*3072;           // 96 steps of BK=32

  __shared__ short As[2][128][40];   // padded 80B rows
  __shared__ short Ws[2][8192];      // unpadded 64B rows, XOR-swizzled slots

  const int wid = t>>6, lane = t&63;

  // ---- A reg-stage ids (transform fused) ----
  const int arow = t>>2, acol = (t&3)<<3;
  const short* aptr = raw + (size_t)(b0+arow)*KTOT + kb0 + acol;

  // ---- W global_load_lds: wave wid covers local rows [wid*32, wid*32+32) ----
  // LDS layout: row n (64B) holds slots s'; logical k-slot = s' ^ ((n>>1)&3)
  const int nl0 = wid*32 + (lane>>2);
  const int nl1 = nl0 + 16;
  const int sl0 = (lane&3) ^ ((nl0>>1)&3);
  const int sl1 = (lane&3) ^ ((nl1>>1)&3);
  const short* wp0 = wT + (size_t)(n0+nl0)*KTOT + kb0 + sl0*8;
  const short* wp1 = wT + (size_t)(n0+nl1)*KTOT + kb0 + sl1*8;
  const int ldsw0 = wid*1024;        // shorts
  const int ldsw1 = wid*1024 + 512;

  f32x4 acc[4][4];
  #pragma unroll
  for (int m=0;m<4;m++)
    #pragma unroll
    for (int n=0;n<4;n++){ f32x4 z = {0.f,0.f,0.f,0.f}; acc[m][n]=z; }

  const int wr = (wid>>2)*64, wc = (wid&3)*64;
  const int fr = lane&15, fkq = lane>>4;      // fk = fkq*8

  // W ds_read byte offsets within a buffer (swizzled), constant per step
  int wroff[4];
  #pragma unroll
  for (int n=0;n<4;n++){
    int r = wc + n*16 + fr;
    wroff[n] = r*64 + ((fkq ^ ((r>>1)&3))<<4);
  }

  // ---- prologue: stage step 0 into buf 0 ----
  GLOAD16(wp0, &Ws[0][ldsw0]);
  GLOAD16(wp1, &Ws[0][ldsw1]);
  s16x8 aReg = *reinterpret_cast<const s16x8*>(aptr);
  int ch = kb0 >> 9;
  float g = gates[ch*NB + b0 + arow];
  float scg = scale[ch]*g, shg = shift[ch]*g;
  {
    s16x8 av;
    #pragma unroll
    for (int j=0;j<8;j++)
      av[j] = f2bf_fast(fmaxf(bf2f(aReg[j])*scg + shg, 0.f));
    *reinterpret_cast<s16x8*>(&As[0][arow][acol]) = av;
  }
  __syncthreads();

  int cur = 0;
  for (int step=0; step<96; ++step){
    const int nxt = cur ^ 1;
    if (step < 95){
      const int ko = (step+1)*32;
      GLOAD16(wp0 + ko, &Ws[nxt][ldsw0]);
      GLOAD16(wp1 + ko, &Ws[nxt][ldsw1]);
      aReg = *reinterpret_cast<const s16x8*>(aptr + ko);
      int nch = (kb0 + ko) >> 9;
      if (nch != ch){
        ch = nch;
        g = gates[ch*NB + b0 + arow];
        scg = scale[ch]*g; shg = shift[ch]*g;
      }
    }
    // MFMA phase on buf[cur]
    {
      const short* asb = &As[cur][0][0];
      const char*  wsb = (const char*)&Ws[cur][0];
      s16x8 af[4], bfm[4];
      #pragma unroll
      for (int m=0;m<4;m++)
        af[m] = *reinterpret_cast<const s16x8*>(asb + (wr + m*16 + fr)*40 + fkq*8);
      #pragma unroll
      for (int n=0;n<4;n++)
        bfm[n] = *reinterpret_cast<const s16x8*>(wsb + wroff[n]);
      #pragma unroll
      for (int m=0;m<4;m++)
        #pragma unroll
        for (int n=0;n<4;n++)
          acc[m][n] = __builtin_amdgcn_mfma_f32_16x16x32_bf16(af[m], bfm[n], acc[m][n], 0,0,0);
    }
    if (step < 95){
      s16x8 av;
      #pragma unroll
      for (int j=0;j<8;j++)
        av[j] = f2bf_fast(fmaxf(bf2f(aReg[j])*scg + shg, 0.f));
      *reinterpret_cast<s16x8*>(&As[nxt][arow][acol]) = av;
    }
    __syncthreads();
    cur = nxt;
  }

  // ---- epilogue: bf16 partials [sk][4096][512] ----
  short* pb = partials + (size_t)sk*NB*NOUT;
  #pragma unroll
  for (int m=0;m<4;m++){
    #pragma unroll
    for (int j=0;j<4;j++){
      int row = b0 + wr + m*16 + (lane>>4)*4 + j;
      short* prow = pb + (size_t)row*NOUT + n0 + wc + fr;
      #pragma unroll
      for (int n=0;n<4;n++) prow[n*16] = f2bf(acc[m][n][j]);
    }
  }
}

// ---------------- kernel 7: split-K reduce + bias -------------------------
__global__ __launch_bounds__(256) void k_red(const short* __restrict__ partials,
                                             const float* __restrict__ fcb,
                                             float* __restrict__ out){
  int i = blockIdx.x*256 + threadIdx.x;          // 524288 threads, 4 outs each
  int base = i*4;
  f32x4 v = *reinterpret_cast<const f32x4*>(fcb + (base & 511));
  #pragma unroll
  for (int sk=0;sk<8;sk++){
    s16x4 p = *reinterpret_cast<const s16x4*>(partials + (size_t)sk*2097152 + base);
    v[0] += bf2f(p[0]); v[1] += bf2f(p[1]);
    v[2] += bf2f(p[2]); v[3] += bf2f(p[3]);
  }
  *reinterpret_cast<f32x4*>(out + base) = v;
}

// ---------------- launch ---------------------------------------------------
extern "C" void kernel_launch(void* const* d_in, const int* in_sizes, int n_in,
                              void* d_out, int out_size, void* d_ws, size_t ws_size,
                              hipStream_t stream) {
  const float* concat = (const float*)d_in[0];
  const int*   rel    = (const int*)  d_in[1];
  const int*   perm   = (const int*)  d_in[2];
  const float* f1t = (const float*)d_in[3];
  const float* f3t = (const float*)d_in[4];
  const float* f5t = (const float*)d_in[5];
  const float* bn0g=(const float*)d_in[6],  *bn0b=(const float*)d_in[7];
  const float* bn1g=(const float*)d_in[8],  *bn1b=(const float*)d_in[9];
  const float* bn2g=(const float*)d_in[10], *bn2b=(const float*)d_in[11];
  const float* bn3g=(const float*)d_in[12], *bn3b=(const float*)d_in[13];
  const float* Wsq=(const float*)d_in[14],  *bsq=(const float*)d_in[15];
  const float* W1=(const float*)d_in[16],   *b1=(const float*)d_in[17];
  const float* W2=(const float*)d_in[18],   *b2=(const float*)d_in[19];
  const float* W3=(const float*)d_in[20],   *b3=(const float*)d_in[21];
  const float* fcW=(const float*)d_in[22],  *fcb=(const float*)d_in[23];
  float* out = (float*)d_out;
  char* ws = (char*)d_ws;

  const size_t off_raw  = 0;                         // 4096*24576*2 = 201326592
  const size_t off_wT   = 201326592;                 // 512*24576*2  = 25165824
  const size_t off_part = 226492416;                 // 8*4096*512*2 = 33554432 (bf16)
  const size_t off_psum = 260046848;                 // 48*4096*4    = 786432
  const size_t off_psq  = 260833280;                 // 786432
  const size_t off_gate = 261619712;                 // 786432
  const size_t off_stat = 262406144;                 // 512
  const size_t off_chm  = 262406656;                 // 4096
  const size_t need     = off_chm + 4096;
  if (ws_size < need) return;  // diagnose: output stays zero -> absmax ~2.86

  short* raw      = (short*)(ws + off_raw);
  short* wT       = (short*)(ws + off_wT);
  short* partials = (short*)(ws + off_part);
  float* psum     = (float*)(ws + off_psum);
  float* psq      = (float*)(ws + off_psq);
  float* gates    = (float*)(ws + off_gate);
  float* statf    = (float*)(ws + off_stat);
  int*   chmap    = (int*)  (ws + off_chm);

  k_colmap<<<4, 256, 0, stream>>>(perm, chmap, statf);
  k_bn0   <<<2048, 256, 0, stream>>>(concat, chmap, statf);
  k_wcast <<<3072, 256, 0, stream>>>(fcW, wT);
  k_conv  <<<4096, 256, 0, stream>>>(concat, perm, rel, f1t, f3t, f5t,
                                     statf, bn0g, bn0b, raw, psum, psq);
  k_bnstats<<<48, 256, 0, stream>>>(psum, psq, bn1g, bn1b, bn2g, bn2b,
                                    bn3g, bn3b, statf);
  k_se    <<<4096, 64, 0, stream>>>(psum, statf, Wsq, bsq, W1, b1, W2, b2,
                                    W3, b3, gates);
  k_gemm  <<<512, 512, 0, stream>>>(raw, wT, statf+16, statf+64, gates, partials);
  k_red   <<<2048, 256, 0, stream>>>(partials, fcb, out);
}

// Round 3
// 358.119 us; speedup vs baseline: 1.1030x; 1.0129x over previous
//
#include <hip/hip_runtime.h>
#include <hip/hip_bf16.h>
#include <stdint.h>

typedef short s16x8 __attribute__((ext_vector_type(8)));
typedef short s16x4 __attribute__((ext_vector_type(4)));
typedef float f32x4 __attribute__((ext_vector_type(4)));

#define NB 4096
#define KTOT 24576
#define NOUT 512
#define NCH 48

__device__ __forceinline__ short f2bf(float f){
  union { float f; uint32_t u; } x; x.f = f;
  uint32_t r = (x.u + 0x7FFFu + ((x.u >> 16) & 1u)) >> 16;
  return (short)r;
}
__device__ __forceinline__ float bf2f(short s){
  union { uint32_t u; float f; } x; x.u = ((uint32_t)(uint16_t)s) << 16;
  return x.f;
}
__device__ __forceinline__ short f2bf_fast(float x){
  union { __hip_bfloat16 h; short s; } c; c.h = __float2bfloat16(x); return c.s;
}

#define GLOAD16(g, l) __builtin_amdgcn_global_load_lds( \
  (const __attribute__((address_space(1))) void*)(g), \
  (__attribute__((address_space(3))) void*)(l), 16, 0, 0)

// ---------------- kernel 0: column->channel map + zero bn0 accumulators ----
__global__ __launch_bounds__(256) void k_colmap(const int* __restrict__ perm,
                                                int* __restrict__ chmap,
                                                float* __restrict__ statf){
  int q = blockIdx.x * 256 + threadIdx.x;
  if (q < 1024) chmap[perm[q]] = q >> 9;
  if (blockIdx.x == 0 && threadIdx.x < 4) statf[threadIdx.x] = 0.f;
}

// ---------------- kernel 1: bn0 batch stats ------------------------------
__global__ __launch_bounds__(256) void k_bn0(const float* __restrict__ concat,
                                             const int* __restrict__ chmap,
                                             float* __restrict__ statf){
  int t = threadIdx.x;
  float s0=0,q0=0,s1=0,q1=0;
  for (int idx = blockIdx.x*256 + t; idx < NB*1024; idx += gridDim.x*256){
    float v = concat[idx];
    int ch = chmap[idx & 1023];
    if (ch){ s1 += v; q1 += v*v; } else { s0 += v; q0 += v*v; }
  }
  #pragma unroll
  for (int m=1;m<64;m<<=1){
    s0 += __shfl_xor(s0,m); q0 += __shfl_xor(q0,m);
    s1 += __shfl_xor(s1,m); q1 += __shfl_xor(q1,m);
  }
  __shared__ float lb[4][4];
  int wid = t>>6, lane = t&63;
  if (lane==0){ lb[wid][0]=s0; lb[wid][1]=q0; lb[wid][2]=s1; lb[wid][3]=q1; }
  __syncthreads();
  if (t==0){
    float a0=0,a1=0,a2=0,a3=0;
    #pragma unroll
    for (int w=0;w<4;w++){ a0+=lb[w][0]; a1+=lb[w][1]; a2+=lb[w][2]; a3+=lb[w][3]; }
    atomicAdd(&statf[0],a0); atomicAdd(&statf[1],a1);
    atomicAdd(&statf[2],a2); atomicAdd(&statf[3],a3);
  }
}

// ---- kernel 2: cast+transpose fc_W -> wTs[n][k] bf16, 16B-granule-swizzled
// within each 64-elem K-tile: logical granule g (8 bf16) stored at slot
// g ^ (n&7), so linear global_load_lds lands the swizzled layout in LDS.
__global__ __launch_bounds__(256) void k_wcast(const float* __restrict__ fcW,
                                               short* __restrict__ wTs){
  __shared__ float tile[64][65];
  int bid = blockIdx.x;
  int kb = (bid % 384) * 64;
  int nb = (bid / 384) * 64;
  int t = threadIdx.x;
  #pragma unroll
  for (int i=0;i<16;i++){
    int r = i*4 + (t>>6), c = t & 63;
    tile[r][c] = fcW[(size_t)(kb + r)*NOUT + nb + c];
  }
  __syncthreads();
  #pragma unroll
  for (int i=0;i<16;i++){
    int n = i*4 + (t>>6), k = t & 63;
    int nr = nb + n;
    int ks = (((k>>3) ^ (nr&7))<<3) | (k&7);
    wTs[(size_t)nr*KTOT + kb + ks] = f2bf(tile[k][n]);
  }
}

// ---------------- kernel 3: per-sample conv (3 branches) ------------------
__global__ __launch_bounds__(256) void k_conv(
    const float* __restrict__ concat, const int* __restrict__ perm,
    const int* __restrict__ rel,
    const float* __restrict__ f1t, const float* __restrict__ f3t,
    const float* __restrict__ f5t,
    const float* __restrict__ statf,
    const float* __restrict__ bn0g, const float* __restrict__ bn0b,
    short* __restrict__ raw, float* __restrict__ psum, float* __restrict__ psq)
{
  const int b = blockIdx.x;
  const int t = threadIdx.x;
  __shared__ float xn[2*9*9*9];     // padded [2][9][9][9], pad = 0
  __shared__ float filt[448];
  for (int i=t;i<1458;i+=256) xn[i]=0.f;
  int r = rel[b];
  for (int i=t;i<448;i+=256){
    float v;
    if (i < 64)       v = f1t[r*64 + i];
    else if (i < 192) v = f3t[r*128 + (i-64)];
    else              v = f5t[r*256 + (i-192)];
    filt[i]=v;
  }
  __syncthreads();
  const float n0inv = 1.f/(4096.f*512.f);
  float m0 = statf[0]*n0inv, e0 = statf[1]*n0inv;
  float m1 = statf[2]*n0inv, e1 = statf[3]*n0inv;
  float sc0 = bn0g[0]*rsqrtf(e0-m0*m0+1e-5f), sh0 = bn0b[0]-m0*sc0;
  float sc1 = bn0g[1]*rsqrtf(e1-m1*m1+1e-5f), sh1 = bn0b[1]-m1*sc1;
  for (int q=t;q<1024;q+=256){
    int col = perm[q];
    float v = concat[(size_t)b*1024 + col];
    int ch = q>>9, s = q & 511;
    int d = s>>6, h=(s>>3)&7, w=s&7;
    xn[ch*729 + d*81 + h*9 + w] = ch ? v*sc1+sh1 : v*sc0+sh0;
  }
  __syncthreads();

  const int wid = t>>6, lane = t&63;
  const int d = lane>>3, h = lane&7;
  float r00[9], r01[9], r10[9], r11[9], r20[9], r21[9], r30[9], r31[9];
  #pragma unroll
  for (int w9=0;w9<9;w9++){
    int base0 = d*81 + h*9 + w9;
    int base1 = d*81 + (h+1)*9 + w9;
    int base2 = (d+1)*81 + h*9 + w9;
    int base3 = (d+1)*81 + (h+1)*9 + w9;
    r00[w9]=xn[base0];      r01[w9]=xn[729+base0];
    r10[w9]=xn[base1];      r11[w9]=xn[729+base1];
    r20[w9]=xn[base2];      r21[w9]=xn[729+base2];
    r30[w9]=xn[base3];      r31[w9]=xn[729+base3];
  }
  const size_t rawbase = (size_t)b*KTOT;

  auto finish = [&](int c, const float* v){
    float s=0,q=0;
    #pragma unroll
    for (int p=0;p<8;p++){ s += v[p]; q += v[p]*v[p]; }
    #pragma unroll
    for (int m=1;m<64;m<<=1){ s += __shfl_xor(s,m); q += __shfl_xor(q,m); }
    if (lane==0){ psum[c*NB+b]=s; psq[c*NB+b]=q; }
    s16x8 pk;
    #pragma unroll
    for (int p=0;p<8;p++) pk[p] = f2bf_fast(v[p]);
    *reinterpret_cast<s16x8*>(raw + rawbase + (size_t)c*512 + lane*8) = pk;
  };

  #pragma unroll
  for (int i=0;i<4;i++){
    int oc = wid + 4*i;
    float c0=filt[oc*4+0], c1=filt[oc*4+1], c2=filt[oc*4+2], c3=filt[oc*4+3];
    float v[8];
    #pragma unroll
    for (int p=0;p<8;p++)
      v[p] = c0*r00[p]+c1*r00[p+1]+c2*r01[p]+c3*r01[p+1];
    finish(oc, v);
  }
  #pragma unroll
  for (int i=0;i<4;i++){
    int oc = wid + 4*i;
    const float* cf = &filt[64 + oc*8];
    float v[8];
    #pragma unroll
    for (int p=0;p<8;p++)
      v[p] = cf[0]*r00[p]+cf[1]*r00[p+1]+cf[2]*r10[p]+cf[3]*r10[p+1]
           + cf[4]*r01[p]+cf[5]*r01[p+1]+cf[6]*r11[p]+cf[7]*r11[p+1];
    finish(16+oc, v);
  }
  #pragma unroll
  for (int i=0;i<4;i++){
    int oc = wid + 4*i;
    const float* cf = &filt[192 + oc*16];
    float v[8];
    #pragma unroll
    for (int p=0;p<8;p++)
      v[p] = cf[0]*r00[p] +cf[1]*r00[p+1] +cf[2]*r10[p] +cf[3]*r10[p+1]
           + cf[4]*r20[p] +cf[5]*r20[p+1] +cf[6]*r30[p] +cf[7]*r30[p+1]
           + cf[8]*r01[p] +cf[9]*r01[p+1] +cf[10]*r11[p]+cf[11]*r11[p+1]
           + cf[12]*r21[p]+cf[13]*r21[p+1]+cf[14]*r31[p]+cf[15]*r31[p+1];
    finish(32+oc, v);
  }
}

// ---------------- kernel 4: finalize bn1/2/3 scale+shift ------------------
__global__ __launch_bounds__(256) void k_bnstats(
    const float* __restrict__ psum, const float* __restrict__ psq,
    const float* __restrict__ bn1g, const float* __restrict__ bn1b,
    const float* __restrict__ bn2g, const float* __restrict__ bn2b,
    const float* __restrict__ bn3g, const float* __restrict__ bn3b,
    float* __restrict__ statf)
{
  int c = blockIdx.x, t = threadIdx.x;
  float s=0,q=0;
  for (int b=t;b<NB;b+=256){ s += psum[c*NB+b]; q += psq[c*NB+b]; }
  #pragma unroll
  for (int m=1;m<64;m<<=1){ s += __shfl_xor(s,m); q += __shfl_xor(q,m); }
  __shared__ float lb[4][2];
  int wid = t>>6, lane = t&63;
  if (lane==0){ lb[wid][0]=s; lb[wid][1]=q; }
  __syncthreads();
  if (t==0){
    s = lb[0][0]+lb[1][0]+lb[2][0]+lb[3][0];
    q = lb[0][1]+lb[1][1]+lb[2][1]+lb[3][1];
    float n = 4096.f*512.f;
    float mean = s/n, var = q/n - mean*mean;
    const float* g  = c<16 ? bn1g : (c<32 ? bn2g : bn3g);
    const float* bb = c<16 ? bn1b : (c<32 ? bn2b : bn3b);
    int oc = c & 15;
    float sc = g[oc]*rsqrtf(var + 1e-5f);
    statf[16+c] = sc;
    statf[64+c] = bb[oc] - mean*sc;
  }
}

// ---------------- kernel 5: SE gates --------------------------------------
__global__ __launch_bounds__(64) void k_se(
    const float* __restrict__ psum, const float* __restrict__ statf,
    const float* __restrict__ Wsq, const float* __restrict__ bsq,
    const float* __restrict__ W1, const float* __restrict__ b1,
    const float* __restrict__ W2, const float* __restrict__ b2,
    const float* __restrict__ W3, const float* __restrict__ b3,
    float* __restrict__ gates)
{
  int b = blockIdx.x, lane = threadIdx.x;
  __shared__ float pooled[16];
  __shared__ float zq[32];
  if (lane < 16){
    float p = 0.f;
    #pragma unroll
    for (int br=0;br<3;br++){
      int c = br*16 + lane;
      p += psum[c*NB+b]*(1.f/512.f)*statf[16+c] + statf[64+c];
    }
    pooled[lane] = p;
  }
  __syncthreads();
  if (lane < 32){
    float z = bsq[lane];
    #pragma unroll
    for (int oc=0;oc<16;oc++) z += pooled[oc]*Wsq[oc*32+lane];
    zq[lane] = fmaxf(z, 0.f);
  }
  __syncthreads();
  if (lane < 48){
    int br = lane>>4, oc = lane&15;
    const float* W  = br==0 ? W1 : (br==1 ? W2 : W3);
    const float* bb = br==0 ? b1 : (br==1 ? b2 : b3);
    float g = bb[oc];
    #pragma unroll
    for (int r2=0;r2<32;r2++) g += zq[r2]*W[r2*16+oc];
    gates[lane*NB + b] = 1.f/(1.f + expf(-g));
  }
}

// ---------------- kernel 6: fused bn+gate+relu GEMM (split-K=8) -----------
// C[4096,512] = A[4096,24576] @ W[24576,512];  A = relu(raw*scg + shg)
// 256x256 tile, BK=64, 8 waves (2M x 4N), counted-vmcnt pipeline, raw
// barriers, 16B-granule XOR swizzle (slot = g ^ (row&7)) on both LDS tiles.
__global__ __launch_bounds__(512, 2) void k_gemm(
    const short* __restrict__ raw, const short* __restrict__ wTs,
    const float* __restrict__ scale, const float* __restrict__ shift,
    const float* __restrict__ gates, short* __restrict__ partials)
{
  const int t = threadIdx.x;
  const int bid = blockIdx.x;
  const int sk = bid >> 5, rem = bid & 31;   // 8 sk x (16 m x 2 n)
  const int nblk = rem >> 4, mblk = rem & 15;
  const int b0 = mblk*256, n0 = nblk*256;
  const int kb0 = sk*3072;                   // 48 K-tiles of 64

  __shared__ short Al[2][256*64];            // 32KB each, swizzled granules
  __shared__ short Wl[2][256*64];
  __shared__ float gsc[6*256];               // gate*scale per (ch, row)
  __shared__ float gsh[6*256];               // gate*shift per (ch, row)

  const int wid = t>>6, lane = t&63;
  const int wm = wid>>2, wn = wid&3;
  const int fr = lane&15, fkq = lane>>4;
  const int sbase = fkq ^ (fr&7);

  // ---- stage per-(channel,row) gate*scale / gate*shift into LDS ----
  for (int i=t; i<1536; i+=512){
    int c = i>>8, r2 = i&255;
    int ch = sk*6 + c;
    float g = gates[(size_t)ch*NB + b0 + r2];
    gsc[i] = scale[ch]*g;
    gsh[i] = shift[ch]*g;
  }
  __syncthreads();   // also leaves vmcnt/lgkmcnt drained: clean counter state

  // ---- A staging ids: thread covers row t>>1, granules (t&1)*4 .. +3 ----
  const int ar = t>>1, ah = t&1;
  const short* aptr = raw + (size_t)(b0+ar)*KTOT + kb0 + ah*32;
  const int arow7 = ar & 7;
  // ---- W gload base: wave covers rows [wid*32, wid*32+32) ----
  const short* wbase = wTs + (size_t)(n0 + wid*32)*KTOT + kb0;
  const int wl_row = lane>>3, wl_g = lane&7;

  f32x4 acc[8][4];
  #pragma unroll
  for (int m=0;m<8;m++)
    #pragma unroll
    for (int n=0;n<4;n++){ f32x4 z = {0.f,0.f,0.f,0.f}; acc[m][n]=z; }

  s16x8 aR[4];

  // ---- prologue: A(0)->regs, W(0)->Wl[0], A(1)->regs, W(1)->Wl[1] ----
  {
    s16x8 aR0[4];
    #pragma unroll
    for (int i=0;i<4;i++) aR0[i] = *reinterpret_cast<const s16x8*>(aptr + i*8);
    asm volatile("" ::: "memory");
    #pragma unroll
    for (int i=0;i<4;i++)
      GLOAD16(wbase + (size_t)(i*8 + wl_row)*KTOT + wl_g*8, &Wl[0][(wid*32 + i*8)*64]);
    asm volatile("" ::: "memory");
    #pragma unroll
    for (int i=0;i<4;i++) aR[i] = *reinterpret_cast<const s16x8*>(aptr + 64 + i*8);
    asm volatile("" ::: "memory");
    #pragma unroll
    for (int i=0;i<4;i++)
      GLOAD16(wbase + (size_t)(i*8 + wl_row)*KTOT + 64 + wl_g*8, &Wl[1][(wid*32 + i*8)*64]);
    asm volatile("s_waitcnt vmcnt(12)" ::: "memory");  // A(0) done
    const float scg = gsc[ar], shg = gsh[ar];          // c = 0
    #pragma unroll
    for (int i=0;i<4;i++){
      s16x8 av;
      #pragma unroll
      for (int j=0;j<8;j++)
        av[j] = f2bf_fast(fmaxf(bf2f(aR0[i][j])*scg + shg, 0.f));
      int slot = (ah*4 + i) ^ arow7;
      *reinterpret_cast<s16x8*>(&Al[0][ar*64 + slot*8]) = av;
    }
    asm volatile("s_waitcnt lgkmcnt(0)" ::: "memory");
    __builtin_amdgcn_s_barrier();
  }

  int cur = 0;
  for (int it=0; it<47; ++it){
    // W(it) complete; newest 8 in flight = A(it+1), W(it+1)
    asm volatile("s_waitcnt vmcnt(8)" ::: "memory");
    const short* Ac = &Al[cur][0];
    const short* Wc = &Wl[cur][0];
    #pragma unroll
    for (int ks=0; ks<2; ks++){
      const int so = ((sbase ^ (ks<<2))<<3);
      s16x8 af[8], bf[4];
      #pragma unroll
      for (int m=0;m<8;m++)
        af[m] = *reinterpret_cast<const s16x8*>(Ac + (wm*128 + m*16 + fr)*64 + so);
      #pragma unroll
      for (int n=0;n<4;n++)
        bf[n] = *reinterpret_cast<const s16x8*>(Wc + (wn*64 + n*16 + fr)*64 + so);
      __builtin_amdgcn_s_setprio(1);
      #pragma unroll
      for (int m=0;m<8;m++)
        #pragma unroll
        for (int n=0;n<4;n++)
          acc[m][n] = __builtin_amdgcn_mfma_f32_16x16x32_bf16(af[m], bf[n], acc[m][n], 0,0,0);
      __builtin_amdgcn_s_setprio(0);
    }
    // A(it+1) regs ready (leaves W(it+1) in flight)
    asm volatile("s_waitcnt vmcnt(4)" ::: "memory");
    {
      const int c = (it+1)>>3;
      const float scg = gsc[c*256 + ar], shg = gsh[c*256 + ar];
      short* An = &Al[cur^1][0];
      #pragma unroll
      for (int i=0;i<4;i++){
        s16x8 av;
        #pragma unroll
        for (int j=0;j<8;j++)
          av[j] = f2bf_fast(fmaxf(bf2f(aR[i][j])*scg + shg, 0.f));
        int slot = (ah*4 + i) ^ arow7;
        *reinterpret_cast<s16x8*>(An + ar*64 + slot*8) = av;
      }
    }
    asm volatile("s_waitcnt lgkmcnt(0)" ::: "memory");
    __builtin_amdgcn_s_barrier();
    if (it < 46){
      const int ko = (it+2)*64;
      #pragma unroll
      for (int i=0;i<4;i++) aR[i] = *reinterpret_cast<const s16x8*>(aptr + ko + i*8);
      asm volatile("" ::: "memory");
      #pragma unroll
      for (int i=0;i<4;i++)
        GLOAD16(wbase + (size_t)(i*8 + wl_row)*KTOT + ko + wl_g*8, &Wl[cur][(wid*32 + i*8)*64]);
      asm volatile("" ::: "memory");
    }
    cur ^= 1;
  }
  // ---- peeled final iter (47): drain everything ----
  asm volatile("s_waitcnt vmcnt(0)" ::: "memory");
  {
    const short* Ac = &Al[cur][0];
    const short* Wc = &Wl[cur][0];
    #pragma unroll
    for (int ks=0; ks<2; ks++){
      const int so = ((sbase ^ (ks<<2))<<3);
      s16x8 af[8], bf[4];
      #pragma unroll
      for (int m=0;m<8;m++)
        af[m] = *reinterpret_cast<const s16x8*>(Ac + (wm*128 + m*16 + fr)*64 + so);
      #pragma unroll
      for (int n=0;n<4;n++)
        bf[n] = *reinterpret_cast<const s16x8*>(Wc + (wn*64 + n*16 + fr)*64 + so);
      __builtin_amdgcn_s_setprio(1);
      #pragma unroll
      for (int m=0;m<8;m++)
        #pragma unroll
        for (int n=0;n<4;n++)
          acc[m][n] = __builtin_amdgcn_mfma_f32_16x16x32_bf16(af[m], bf[n], acc[m][n], 0,0,0);
      __builtin_amdgcn_s_setprio(0);
    }
  }

  // ---- epilogue: bf16 partials [sk][4096][512] ----
  short* pb = partials + (size_t)sk*NB*NOUT;
  #pragma unroll
  for (int m=0;m<8;m++){
    #pragma unroll
    for (int j=0;j<4;j++){
      int row = b0 + wm*128 + m*16 + fkq*4 + j;
      short* prow = pb + (size_t)row*NOUT + n0 + wn*64 + fr;
      #pragma unroll
      for (int n=0;n<4;n++) prow[n*16] = f2bf_fast(acc[m][n][j]);
    }
  }
}

// ---------------- kernel 7: split-K reduce + bias -------------------------
__global__ __launch_bounds__(256) void k_red(const short* __restrict__ partials,
                                             const float* __restrict__ fcb,
                                             float* __restrict__ out){
  int i = blockIdx.x*256 + threadIdx.x;          // 524288 threads, 4 outs each
  int base = i*4;
  f32x4 v = *reinterpret_cast<const f32x4*>(fcb + (base & 511));
  #pragma unroll
  for (int sk=0;sk<8;sk++){
    s16x4 p = *reinterpret_cast<const s16x4*>(partials + (size_t)sk*2097152 + base);
    v[0] += bf2f(p[0]); v[1] += bf2f(p[1]);
    v[2] += bf2f(p[2]); v[3] += bf2f(p[3]);
  }
  *reinterpret_cast<f32x4*>(out + base) = v;
}

// ---------------- launch ---------------------------------------------------
extern "C" void kernel_launch(void* const* d_in, const int* in_sizes, int n_in,
                              void* d_out, int out_size, void* d_ws, size_t ws_size,
                              hipStream_t stream) {
  const float* concat = (const float*)d_in[0];
  const int*   rel    = (const int*)  d_in[1];
  const int*   perm   = (const int*)  d_in[2];
  const float* f1t = (const float*)d_in[3];
  const float* f3t = (const float*)d_in[4];
  const float* f5t = (const float*)d_in[5];
  const float* bn0g=(const float*)d_in[6],  *bn0b=(const float*)d_in[7];
  const float* bn1g=(const float*)d_in[8],  *bn1b=(const float*)d_in[9];
  const float* bn2g=(const float*)d_in[10], *bn2b=(const float*)d_in[11];
  const float* bn3g=(const float*)d_in[12], *bn3b=(const float*)d_in[13];
  const float* Wsq=(const float*)d_in[14],  *bsq=(const float*)d_in[15];
  const float* W1=(const float*)d_in[16],   *b1=(const float*)d_in[17];
  const float* W2=(const float*)d_in[18],   *b2=(const float*)d_in[19];
  const float* W3=(const float*)d_in[20],   *b3=(const float*)d_in[21];
  const float* fcW=(const float*)d_in[22],  *fcb=(const float*)d_in[23];
  float* out = (float*)d_out;
  char* ws = (char*)d_ws;

  const size_t off_raw  = 0;                         // 4096*24576*2 = 201326592
  const size_t off_wT   = 201326592;                 // 512*24576*2  = 25165824
  const size_t off_part = 226492416;                 // 8*4096*512*2 = 33554432 (bf16)
  const size_t off_psum = 260046848;                 // 48*4096*4    = 786432
  const size_t off_psq  = 260833280;                 // 786432
  const size_t off_gate = 261619712;                 // 786432
  const size_t off_stat = 262406144;                 // 512
  const size_t off_chm  = 262406656;                 // 4096
  const size_t need     = off_chm + 4096;
  if (ws_size < need) return;  // diagnose: output stays zero -> absmax ~2.86

  short* raw      = (short*)(ws + off_raw);
  short* wTs      = (short*)(ws + off_wT);
  short* partials = (short*)(ws + off_part);
  float* psum     = (float*)(ws + off_psum);
  float* psq      = (float*)(ws + off_psq);
  float* gates    = (float*)(ws + off_gate);
  float* statf    = (float*)(ws + off_stat);
  int*   chmap    = (int*)  (ws + off_chm);

  k_colmap<<<4, 256, 0, stream>>>(perm, chmap, statf);
  k_bn0   <<<2048, 256, 0, stream>>>(concat, chmap, statf);
  k_wcast <<<3072, 256, 0, stream>>>(fcW, wTs);
  k_conv  <<<4096, 256, 0, stream>>>(concat, perm, rel, f1t, f3t, f5t,
                                     statf, bn0g, bn0b, raw, psum, psq);
  k_bnstats<<<48, 256, 0, stream>>>(psum, psq, bn1g, bn1b, bn2g, bn2b,
                                    bn3g, bn3b, statf);
  k_se    <<<4096, 64, 0, stream>>>(psum, statf, Wsq, bsq, W1, b1, W2, b2,
                                    W3, b3, gates);
  k_gemm  <<<256, 512, 0, stream>>>(raw, wTs, statf+16, statf+64, gates, partials);
  k_red   <<<2048, 256, 0, stream>>>(partials, fcb, out);
}